// Round 1
// baseline (233.817 us; speedup 1.0000x reference)
//
#include <hip/hip_runtime.h>

// JointBilateralFilter: B=16,C=1,H=768,W=1024 fp32, 9x9 window, sigma_s=2, sigma_r=0.1.
// Key facts derived from the reference:
//  * valid = (sparse != 1.0); sparse is constant-padded with 1.0 => out-of-image taps
//    NEVER contribute (valid=0 kills both num and den). Reflect padding of depth is
//    mathematically dead code. No padding needed.
//  * only ~5% of pixels are valid => build a per-tile list of valid points and iterate
//    it, instead of the dense 81-tap loop (81 exps/pixel -> ~13 list entries/pixel).
//  * spatial+range weights fuse: w = exp2(A*(dy^2+dx^2) + B*diff^2),
//    A = -log2(e)/(2*sigma_s^2) = -log2(e)/8, B = -50*log2(e).

#define HH 768
#define WW 1024
#define BB 16

#if defined(__has_builtin)
#  if __has_builtin(__builtin_amdgcn_exp2f)
#    define FAST_EXP2(x) __builtin_amdgcn_exp2f(x)
#  endif
#endif
#ifndef FAST_EXP2
#  define FAST_EXP2(x) exp2f(x)
#endif

#define COEF_S (-0.18033688011112042f)   /* -log2(e)/8      */
#define COEF_R (-72.13475204444817f)     /* -50*log2(e)     */

__global__ __launch_bounds__(64) void jbf_kernel(
    const float* __restrict__ sparse,
    const float* __restrict__ depth,
    float* __restrict__ out)
{
    const int lane = (int)threadIdx.x;                 // 0..63, one wave per block
    const int tx = (int)blockIdx.x << 3;               // 8x8 output tile
    const int ty = (int)blockIdx.y << 3;
    const size_t plane = (size_t)blockIdx.z * (size_t)(HH * WW);
    const float* sp = sparse + plane;
    const float* dp = depth + plane;

    __shared__ float4 list[256];                       // worst case: whole 16x16 region valid

    const int my = lane >> 3, mx = lane & 7;
    const int gy = ty + my, gx = tx + mx;
    const float myd = dp[gy * WW + gx];

    // ---- build the valid-point list over the 16x16 halo region [ty-4,ty+11]x[tx-4,tx+11]
    // single wave => ballot-compaction, no atomics, deterministic order.
    int cnt = 0;
    #pragma unroll
    for (int it = 0; it < 4; ++it) {
        const int idx = (it << 6) + lane;              // 0..255
        const int ry = idx >> 4, rx = idx & 15;
        const int py = ty - 4 + ry;
        const int px = tx - 4 + rx;
        const bool inb = (py >= 0) & (py < HH) & (px >= 0) & (px < WW);
        float sv = 1.0f;
        if (inb) sv = sp[py * WW + px];
        const bool valid = inb && (sv != 1.0f);
        const unsigned long long mask = __ballot(valid);
        if (valid) {
            const int pos = cnt + (int)__popcll(mask & ((1ull << lane) - 1ull));
            const float dv = dp[py * WW + px];
            list[pos] = make_float4((float)py, (float)px, sv, dv);
        }
        cnt += (int)__popcll(mask);                    // cnt is wave-uniform
    }
    __syncthreads();

    // ---- iterate the list; entries are wave-uniform => ds_read_b128 broadcast
    const float fy = (float)gy, fx = (float)gx;
    float num = 0.0f, den = 0.0f;
    for (int j = 0; j < cnt; ++j) {
        const float4 p = list[j];
        const float dy = p.x - fy;
        const float dx = p.y - fx;
        const float box = fmaxf(fabsf(dy), fabsf(dx)); // Chebyshev distance: 9x9 box test
        const float r2 = fmaf(dy, dy, dx * dx);
        const float diff = p.w - myd;
        const float arg = fmaf(diff * diff, COEF_R, r2 * COEF_S);
        float w = FAST_EXP2(arg);
        w = (box <= 4.0f) ? w : 0.0f;
        num = fmaf(w, p.z, num);
        den += w;
    }

    const float res = (den < 1e-8f) ? 1.0f : num / (den + 1e-8f);
    out[plane + (size_t)(gy * WW + gx)] = res;
}

extern "C" void kernel_launch(void* const* d_in, const int* in_sizes, int n_in,
                              void* d_out, int out_size, void* d_ws, size_t ws_size,
                              hipStream_t stream)
{
    const float* sparse = (const float*)d_in[0];
    const float* depth  = (const float*)d_in[1];
    float* out = (float*)d_out;
    dim3 grid(WW / 8, HH / 8, BB);   // 128 x 96 x 16 blocks, exact tiling
    jbf_kernel<<<grid, dim3(64, 1, 1), 0, stream>>>(sparse, depth, out);
}